// Round 1
// baseline (2039.384 us; speedup 1.0000x reference)
//
#include <hip/hip_runtime.h>
#include <hip/hip_bf16.h>
#include <math.h>

#define EPSV 1e-5f

__device__ __forceinline__ float silu_f(float v) { return v / (1.0f + __expf(-v)); }

// ---------------- 4x4 average pool: x[8,256,128,128] -> xkv[8,256,32,32] ----------------
__global__ __launch_bounds__(256) void pool_kernel(const float* __restrict__ x,
                                                   float* __restrict__ xkv) {
  int idx = blockIdx.x * 256 + threadIdx.x;  // [b*c][1024]
  int m = idx & 1023, bc = idx >> 10;
  int hh = m >> 5, ww = m & 31;
  const float* base = x + ((size_t)bc << 14) + (size_t)(hh * 4) * 128 + ww * 4;
  float s = 0.f;
#pragma unroll
  for (int i = 0; i < 4; ++i) {
    float4 v = *reinterpret_cast<const float4*>(base + i * 128);
    s += v.x + v.y + v.z + v.w;
  }
  xkv[idx] = s * 0.0625f;
}

// ---------------- transpose pw_w[256][256] -> pwt[c][o] ----------------
__global__ __launch_bounds__(256) void transpose_pw(const float* __restrict__ pw,
                                                    float* __restrict__ pwt) {
  __shared__ float t[32][33];
  int lx = threadIdx.x & 31, ly = threadIdx.x >> 5;
#pragma unroll
  for (int i = 0; i < 4; ++i)
    t[ly + i * 8][lx] = pw[(blockIdx.y * 32 + ly + i * 8) * 256 + blockIdx.x * 32 + lx];
  __syncthreads();
#pragma unroll
  for (int i = 0; i < 4; ++i)
    pwt[(blockIdx.x * 32 + ly + i * 8) * 256 + blockIdx.y * 32 + lx] = t[lx][ly + i * 8];
}

// ---------------- C[b][R][Ncol] = alpha * W[R][256] @ X[b][256][Ncol] ----------------
__global__ __launch_bounds__(256, 4) void gemm_wx(const float* __restrict__ W,
                                                  const float* __restrict__ X,
                                                  float* __restrict__ C, int Ncol, float alpha) {
  __shared__ float sW[64 * 68];
  __shared__ float sX[64 * 68];
  const int tid = threadIdx.x;
  const int n0 = blockIdx.x * 64, m0 = blockIdx.y * 64;
  const size_t xoff = (size_t)blockIdx.z * 256 * (size_t)Ncol;
  const int tm4 = (tid >> 4) * 4, tn4 = (tid & 15) * 4;
  float acc[4][4] = {};
  for (int k0 = 0; k0 < 256; k0 += 64) {
    __syncthreads();
#pragma unroll
    for (int i = 0; i < 16; ++i) {
      int flat = tid + i * 256;
      int kk = flat & 63, mm = flat >> 6;
      sW[kk * 68 + mm] = W[(m0 + mm) * 256 + k0 + kk];
      sX[kk * 68 + mm] = X[xoff + (size_t)(k0 + kk) * Ncol + n0 + mm];
    }
    __syncthreads();
#pragma unroll 8
    for (int k = 0; k < 64; ++k) {
      float4 a4 = *reinterpret_cast<const float4*>(&sW[k * 68 + tm4]);
      float4 b4 = *reinterpret_cast<const float4*>(&sX[k * 68 + tn4]);
      float av[4] = {a4.x, a4.y, a4.z, a4.w};
      float bv[4] = {b4.x, b4.y, b4.z, b4.w};
#pragma unroll
      for (int i = 0; i < 4; ++i)
#pragma unroll
        for (int j = 0; j < 4; ++j) acc[i][j] += av[i] * bv[j];
    }
  }
  const size_t coff = (size_t)blockIdx.z * (size_t)(gridDim.y * 64) * Ncol;
#pragma unroll
  for (int i = 0; i < 4; ++i) {
    float4 o = make_float4(acc[i][0] * alpha, acc[i][1] * alpha, acc[i][2] * alpha,
                           acc[i][3] * alpha);
    *reinterpret_cast<float4*>(&C[coff + (size_t)(m0 + tm4 + i) * Ncol + n0 + tn4]) = o;
  }
}

// ---------------- fused attention + proj + BN + SiLU -> yact (bf16) ----------------
// Per block: batch b, 64 queries. Online softmax over M=1024 in chunks of 64.
__global__ __launch_bounds__(256, 2) void attn_kernel(
    const float* __restrict__ Q, const float* __restrict__ K, const float* __restrict__ V,
    const float* __restrict__ wproj, const float* __restrict__ bng,
    const float* __restrict__ bnb, const float* __restrict__ bnm,
    const float* __restrict__ bnv, __hip_bfloat16* __restrict__ yact) {
  __shared__ float sQ[64 * 68];    // [a][q]
  __shared__ float sKP[64 * 68];   // [a][m], reused as P[q][m]
  __shared__ float sVY[128 * 66];  // [vc][m], reused as Y[vc][q]
  const int tid = threadIdx.x;
  const int b = blockIdx.y;
  const int n0 = blockIdx.x * 64;
  const int tq = tid >> 4, tm = tid & 15;
  const float* Qb = Q + (size_t)b * 64 * 16384 + n0;
#pragma unroll
  for (int i = 0; i < 16; ++i) {
    int flat = tid + i * 256;
    int a = flat >> 6, q = flat & 63;
    sQ[a * 68 + q] = Qb[(size_t)a * 16384 + q];
  }
  float mrun[4], lrun[4], acc[4][8];
#pragma unroll
  for (int i = 0; i < 4; ++i) {
    mrun[i] = -INFINITY; lrun[i] = 0.f;
#pragma unroll
    for (int j = 0; j < 8; ++j) acc[i][j] = 0.f;
  }
  const float* Kb = K + (size_t)b * 64 * 1024;
  const float* Vb = V + (size_t)b * 128 * 1024;
  for (int mc = 0; mc < 1024; mc += 64) {
    __syncthreads();
#pragma unroll
    for (int i = 0; i < 16; ++i) {
      int flat = tid + i * 256;
      int a = flat >> 6, m = flat & 63;
      sKP[a * 68 + m] = Kb[a * 1024 + mc + m];
    }
#pragma unroll
    for (int i = 0; i < 32; ++i) {
      int flat = tid + i * 256;
      int vc = flat >> 6, m = flat & 63;
      sVY[vc * 66 + m] = Vb[vc * 1024 + mc + m];
    }
    __syncthreads();
    // S[q][m], q = 4tq+i, m = 4tm+j (scale already folded into Q)
    float s[4][4] = {};
#pragma unroll 8
    for (int a = 0; a < 64; ++a) {
      float4 qv = *reinterpret_cast<const float4*>(&sQ[a * 68 + tq * 4]);
      float4 kv = *reinterpret_cast<const float4*>(&sKP[a * 68 + tm * 4]);
      float qa[4] = {qv.x, qv.y, qv.z, qv.w};
      float ka[4] = {kv.x, kv.y, kv.z, kv.w};
#pragma unroll
      for (int i = 0; i < 4; ++i)
#pragma unroll
        for (int j = 0; j < 4; ++j) s[i][j] += qa[i] * ka[j];
    }
    float p[4][4], rescale[4];
#pragma unroll
    for (int i = 0; i < 4; ++i) {
      float rm = fmaxf(fmaxf(s[i][0], s[i][1]), fmaxf(s[i][2], s[i][3]));
      rm = fmaxf(rm, __shfl_xor(rm, 1, 16));
      rm = fmaxf(rm, __shfl_xor(rm, 2, 16));
      rm = fmaxf(rm, __shfl_xor(rm, 4, 16));
      rm = fmaxf(rm, __shfl_xor(rm, 8, 16));
      float mnew = fmaxf(mrun[i], rm);
      rescale[i] = __expf(mrun[i] - mnew);
      mrun[i] = mnew;
      float sum = 0.f;
#pragma unroll
      for (int j = 0; j < 4; ++j) { p[i][j] = __expf(s[i][j] - mnew); sum += p[i][j]; }
      sum += __shfl_xor(sum, 1, 16);
      sum += __shfl_xor(sum, 2, 16);
      sum += __shfl_xor(sum, 4, 16);
      sum += __shfl_xor(sum, 8, 16);
      lrun[i] = lrun[i] * rescale[i] + sum;
#pragma unroll
      for (int j = 0; j < 8; ++j) acc[i][j] *= rescale[i];
    }
    __syncthreads();  // all sKP (K) reads done -> safe to overwrite with P
#pragma unroll
    for (int i = 0; i < 4; ++i)
      *reinterpret_cast<float4*>(&sKP[(tq * 4 + i) * 68 + tm * 4]) =
          make_float4(p[i][0], p[i][1], p[i][2], p[i][3]);
    __syncthreads();
    // acc[i][j] += sum_mm P[4tq+i][mm] * V[tm+16j][mm]
#pragma unroll 8
    for (int mm = 0; mm < 64; mm += 2) {
      float2 pp[4];
#pragma unroll
      for (int i = 0; i < 4; ++i)
        pp[i] = *reinterpret_cast<const float2*>(&sKP[(tq * 4 + i) * 68 + mm]);
#pragma unroll
      for (int j = 0; j < 8; ++j) {
        float2 vv = *reinterpret_cast<const float2*>(&sVY[(tm + 16 * j) * 66 + mm]);
#pragma unroll
        for (int i = 0; i < 4; ++i) acc[i][j] += pp[i].x * vv.x + pp[i].y * vv.y;
      }
    }
  }
  __syncthreads();
  // normalize, store Y[vc][q] into sVY
#pragma unroll
  for (int i = 0; i < 4; ++i) {
    float invl = 1.0f / lrun[i];
#pragma unroll
    for (int j = 0; j < 8; ++j) sVY[(tm + 16 * j) * 66 + tq * 4 + i] = acc[i][j] * invl;
  }
  __syncthreads();
  // proj + BN + SiLU: lane = q, wave-uniform output channel
  const int lane = tid & 63;
  const int wvid = __builtin_amdgcn_readfirstlane(tid >> 6);
  for (int chunk = 0; chunk < 8; ++chunk) {
    const int cbase = wvid * 64 + chunk * 8;
    float pacc[8] = {};
    for (int v = 0; v < 128; ++v) {
      float yv = sVY[v * 66 + lane];
#pragma unroll
      for (int k2 = 0; k2 < 8; ++k2) pacc[k2] += wproj[(cbase + k2) * 128 + v] * yv;
    }
#pragma unroll
    for (int k2 = 0; k2 < 8; ++k2) {
      int c = cbase + k2;
      float inv = bng[c] / sqrtf(bnv[c] + EPSV);
      float val = pacc[k2] * inv + (bnb[c] - bnm[c] * inv);
      yact[((size_t)b * 256 + c) * 16384 + n0 + lane] = __float2bfloat16(silu_f(val));
    }
  }
}

// ---------------- dw3x3 + pointwise mix + BN + SiLU + residual ----------------
// Block: 32x2 spatial tile, all 256 channels. acc GEMM: [256 o] x [256 c] x [64 px].
__global__ __launch_bounds__(256, 2) void dwpw_kernel(
    const __hip_bfloat16* __restrict__ yact, const float* __restrict__ dww,
    const float* __restrict__ pwt, const float* __restrict__ x,
    const float* __restrict__ mg, const float* __restrict__ mb2,
    const float* __restrict__ mmu, const float* __restrict__ mvv,
    float* __restrict__ out) {
  __shared__ float sH[4 * 4 * 36];   // 4 channels, 4 rows, 34(+2 pad) cols halo
  __shared__ float sD[4 * 64];       // dw-conv result, 4 channels x 64 px
  __shared__ float sOut[256 * 65];   // staging for coalesced writes
  const int tid = threadIdx.x;
  const int b = blockIdx.z;
  const int r0 = blockIdx.y * 2;
  const int c0 = blockIdx.x * 32;
  float acc[4][16] = {};
  const int o0 = (tid & 63) * 4;  // 4 output channels per thread
  const int ph = tid >> 6;        // wave id -> 16-px slice
  const int dcc = tid >> 6, dp = tid & 63, dpr = dp >> 5, dpc = dp & 31;
  for (int c = 0; c < 256; c += 4) {
    __syncthreads();
    for (int s = tid; s < 544; s += 256) {
      int cc = s / 136, rem = s % 136;
      int r = rem / 34, col = rem % 34;
      int gr = r0 - 1 + r, gc = c0 - 1 + col;
      float v = 0.f;
      if (gr >= 0 && gr < 128 && gc >= 0 && gc < 128)
        v = __bfloat162float(yact[(((size_t)b * 256 + c + cc) * 128 + gr) * 128 + gc]);
      sH[(cc * 4 + r) * 36 + col] = v;
    }
    __syncthreads();
    {
      const float* w9 = dww + (c + dcc) * 9;  // dcc wave-uniform -> scalar loads
      float sum = 0.f;
#pragma unroll
      for (int i = 0; i < 3; ++i)
#pragma unroll
        for (int j = 0; j < 3; ++j)
          sum += sH[(dcc * 4 + dpr + i) * 36 + dpc + j] * w9[i * 3 + j];
      sD[dcc * 64 + dp] = sum;
    }
    __syncthreads();
#pragma unroll
    for (int cc = 0; cc < 4; ++cc) {
      float4 w4 = *reinterpret_cast<const float4*>(&pwt[(c + cc) * 256 + o0]);
      const float4* d4p = reinterpret_cast<const float4*>(&sD[cc * 64 + ph * 16]);
      float wv4[4] = {w4.x, w4.y, w4.z, w4.w};
#pragma unroll
      for (int k = 0; k < 4; ++k) {
        float4 d = d4p[k];
        float dv[4] = {d.x, d.y, d.z, d.w};
#pragma unroll
        for (int oi = 0; oi < 4; ++oi)
#pragma unroll
          for (int kk = 0; kk < 4; ++kk) acc[oi][k * 4 + kk] += wv4[oi] * dv[kk];
      }
    }
  }
  __syncthreads();
#pragma unroll
  for (int oi = 0; oi < 4; ++oi)
#pragma unroll
    for (int k = 0; k < 16; ++k) sOut[(o0 + oi) * 65 + ph * 16 + k] = acc[oi][k];
  __syncthreads();
  const int lane = tid & 63;
  for (int i = 0; i < 64; ++i) {
    int o = (tid >> 6) + i * 4;  // wave-uniform
    float z = sOut[o * 65 + lane];
    float inv = mg[o] / sqrtf(mvv[o] + EPSV);
    float zb = z * inv + (mb2[o] - mmu[o] * inv);
    int pr = lane >> 5, pc = lane & 31;
    size_t gidx = (((size_t)b * 256 + o) * 128 + r0 + pr) * 128 + c0 + pc;
    out[gidx] = x[gidx] + silu_f(zb);
  }
}

extern "C" void kernel_launch(void* const* d_in, const int* in_sizes, int n_in,
                              void* d_out, int out_size, void* d_ws, size_t ws_size,
                              hipStream_t stream) {
  const float* x     = (const float*)d_in[0];
  const float* wq    = (const float*)d_in[1];
  const float* wk    = (const float*)d_in[2];
  const float* wvp   = (const float*)d_in[3];
  const float* wproj = (const float*)d_in[4];
  const float* bng   = (const float*)d_in[5];
  const float* bnb   = (const float*)d_in[6];
  const float* bnm   = (const float*)d_in[7];
  const float* bnv   = (const float*)d_in[8];
  const float* dww   = (const float*)d_in[9];
  const float* pww   = (const float*)d_in[10];
  const float* mg    = (const float*)d_in[11];
  const float* mb2   = (const float*)d_in[12];
  const float* mmu   = (const float*)d_in[13];
  const float* mvv   = (const float*)d_in[14];
  float* out = (float*)d_out;

  float* ws  = (float*)d_ws;
  float* xkv = ws;                 // 8*256*1024        = 2,097,152 f
  float* Qw  = xkv + 2097152;      // 8*64*16384        = 8,388,608 f
  float* Kw  = Qw + 8388608;       // 8*64*1024         =   524,288 f
  float* Vw  = Kw + 524288;        // 8*128*1024        = 1,048,576 f
  float* pwt = Vw + 1048576;       // 256*256           =    65,536 f
  __hip_bfloat16* yact = (__hip_bfloat16*)(pwt + 65536);  // 8*256*16384 bf16

  pool_kernel<<<8192, 256, 0, stream>>>(x, xkv);
  transpose_pw<<<dim3(8, 8), 256, 0, stream>>>(pww, pwt);
  gemm_wx<<<dim3(256, 1, 8), 256, 0, stream>>>(wq, x, Qw, 16384, 0.125f);   // Q (scale folded)
  gemm_wx<<<dim3(16, 1, 8), 256, 0, stream>>>(wk, xkv, Kw, 1024, 1.0f);     // K
  gemm_wx<<<dim3(16, 2, 8), 256, 0, stream>>>(wvp, xkv, Vw, 1024, 1.0f);    // V
  attn_kernel<<<dim3(256, 8), 256, 0, stream>>>(Qw, Kw, Vw, wproj, bng, bnb, bnm, bnv, yact);
  dwpw_kernel<<<dim3(4, 64, 8), 256, 0, stream>>>(yact, dww, pwt, x, mg, mb2, mmu, mvv, out);
}

// Round 2
// 982.393 us; speedup vs baseline: 2.0759x; 2.0759x over previous
//
#include <hip/hip_runtime.h>
#include <hip/hip_bf16.h>
#include <math.h>

#define EPSV 1e-5f

typedef short bf16x8 __attribute__((ext_vector_type(8)));
typedef float f32x16 __attribute__((ext_vector_type(16)));
typedef unsigned int uint4v __attribute__((ext_vector_type(4)));

__device__ __forceinline__ float silu_f(float v) { return v / (1.0f + __expf(-v)); }

__device__ __forceinline__ unsigned short f2bf(float f) {
  __hip_bfloat16 h = __float2bfloat16(f);
  return __builtin_bit_cast(unsigned short, h);
}

__device__ __forceinline__ bf16x8 ld_frag(const unsigned short* p) {
  return *reinterpret_cast<const bf16x8*>(p);
}

// ---------------- 4x4 average pool: x[8,256,128,128] -> xkv[8,256,32,32] ----------------
__global__ __launch_bounds__(256) void pool_kernel(const float* __restrict__ x,
                                                   float* __restrict__ xkv) {
  int idx = blockIdx.x * 256 + threadIdx.x;
  int m = idx & 1023, bc = idx >> 10;
  int hh = m >> 5, ww = m & 31;
  const float* base = x + ((size_t)bc << 14) + (size_t)(hh * 4) * 128 + ww * 4;
  float s = 0.f;
#pragma unroll
  for (int i = 0; i < 4; ++i) {
    float4 v = *reinterpret_cast<const float4*>(base + i * 128);
    s += v.x + v.y + v.z + v.w;
  }
  xkv[idx] = s * 0.0625f;
}

// ---------------- transpose pw_w[256][256] -> pwt[c][o] ----------------
__global__ __launch_bounds__(256) void transpose_pw(const float* __restrict__ pw,
                                                    float* __restrict__ pwt) {
  __shared__ float t[32][33];
  int lx = threadIdx.x & 31, ly = threadIdx.x >> 5;
#pragma unroll
  for (int i = 0; i < 4; ++i)
    t[ly + i * 8][lx] = pw[(blockIdx.y * 32 + ly + i * 8) * 256 + blockIdx.x * 32 + lx];
  __syncthreads();
#pragma unroll
  for (int i = 0; i < 4; ++i)
    pwt[(blockIdx.x * 32 + ly + i * 8) * 256 + blockIdx.y * 32 + lx] = t[lx][ly + i * 8];
}

// ---------------- prep: wproj->bf16, BN scale/shift ----------------
__global__ __launch_bounds__(256) void prep_kernel(const float* __restrict__ wproj,
                                                   const float* __restrict__ bng,
                                                   const float* __restrict__ bnb,
                                                   const float* __restrict__ bnm,
                                                   const float* __restrict__ bnv,
                                                   unsigned short* __restrict__ wpb,
                                                   float* __restrict__ bnsc,
                                                   float* __restrict__ bnsh) {
  int i = blockIdx.x * 256 + threadIdx.x;
  if (i < 32768) wpb[i] = f2bf(wproj[i]);
  else if (i < 33024) {
    int c = i - 32768;
    float inv = bng[c] / sqrtf(bnv[c] + EPSV);
    bnsc[c] = inv;
    bnsh[c] = bnb[c] - bnm[c] * inv;
  }
}

// ---------------- C = alpha * W[R][256] @ X[b][256][Ncol], bf16 out ----------------
// MODE 1: transposed out Ct[b][Ncol][R] (R = gridDim.y*64).  MODE 2: direct C[b][R][Ncol].
template <int MODE>
__global__ __launch_bounds__(256, 4) void gemm_wx(const float* __restrict__ W,
                                                  const float* __restrict__ X,
                                                  unsigned short* __restrict__ C, int Ncol,
                                                  float alpha) {
  __shared__ float sW[64 * 68];
  __shared__ float sX[64 * 68];
  const int tid = threadIdx.x;
  const int n0 = blockIdx.x * 64, m0 = blockIdx.y * 64;
  const int Rows = gridDim.y * 64;
  const size_t xoff = (size_t)blockIdx.z * 256 * (size_t)Ncol;
  const int tm4 = (tid >> 4) * 4, tn4 = (tid & 15) * 4;
  float acc[4][4] = {};
  for (int k0 = 0; k0 < 256; k0 += 64) {
    __syncthreads();
#pragma unroll
    for (int i = 0; i < 16; ++i) {
      int flat = tid + i * 256;
      int kk = flat & 63, mm = flat >> 6;
      sW[kk * 68 + mm] = W[(m0 + mm) * 256 + k0 + kk];
      sX[kk * 68 + mm] = X[xoff + (size_t)(k0 + kk) * Ncol + n0 + mm];
    }
    __syncthreads();
#pragma unroll 8
    for (int k = 0; k < 64; ++k) {
      float4 a4 = *reinterpret_cast<const float4*>(&sW[k * 68 + tm4]);
      float4 b4 = *reinterpret_cast<const float4*>(&sX[k * 68 + tn4]);
      float av[4] = {a4.x, a4.y, a4.z, a4.w};
      float bv[4] = {b4.x, b4.y, b4.z, b4.w};
#pragma unroll
      for (int i = 0; i < 4; ++i)
#pragma unroll
        for (int j = 0; j < 4; ++j) acc[i][j] += av[i] * bv[j];
    }
  }
  if (MODE == 1) {
    const size_t coff = (size_t)blockIdx.z * (size_t)Ncol * Rows;
#pragma unroll
    for (int j = 0; j < 4; ++j) {
      ushort4 o;
      o.x = f2bf(acc[0][j] * alpha); o.y = f2bf(acc[1][j] * alpha);
      o.z = f2bf(acc[2][j] * alpha); o.w = f2bf(acc[3][j] * alpha);
      *reinterpret_cast<ushort4*>(&C[coff + (size_t)(n0 + tn4 + j) * Rows + m0 + tm4]) = o;
    }
  } else {
    const size_t coff = (size_t)blockIdx.z * (size_t)Rows * Ncol;
#pragma unroll
    for (int i = 0; i < 4; ++i) {
      ushort4 o;
      o.x = f2bf(acc[i][0] * alpha); o.y = f2bf(acc[i][1] * alpha);
      o.z = f2bf(acc[i][2] * alpha); o.w = f2bf(acc[i][3] * alpha);
      *reinterpret_cast<ushort4*>(&C[coff + (size_t)(m0 + tm4 + i) * Ncol + n0 + tn4]) = o;
    }
  }
}

// ---------------- MFMA flash attention + proj + BN + SiLU -> yact bf16 ----------------
// 4 waves x 32 queries. Swapped QK^T (mfma(K,Q)) => P lane-local per q-column.
// K/V fragments straight from global (L2-resident). Proj fused via per-wave LDS O-tile.
__global__ __launch_bounds__(256, 2) void attn_mfma(
    const unsigned short* __restrict__ Qt, const unsigned short* __restrict__ Kt,
    const unsigned short* __restrict__ Vb, const unsigned short* __restrict__ wpb,
    const float* __restrict__ bnsc, const float* __restrict__ bnsh,
    unsigned short* __restrict__ yact) {
  __shared__ unsigned short sO[4][32 * 128];  // per-wave O[q][vc], XOR-swizzled
  const int tid = threadIdx.x;
  const int w = tid >> 6, l = tid & 63;
  const int lq = l & 31, hi = l >> 5;
  const int b = blockIdx.y;
  const int q0 = blockIdx.x * 128 + w * 32;

  // Q B-fragments (q = lq, a contiguous), kept in registers
  const unsigned short* Qp = Qt + ((size_t)b * 16384 + q0 + lq) * 64 + hi * 8;
  bf16x8 qf[4];
#pragma unroll
  for (int kc = 0; kc < 4; ++kc) qf[kc] = ld_frag(Qp + kc * 16);

  f32x16 acc[4];
#pragma unroll
  for (int t = 0; t < 4; ++t)
#pragma unroll
    for (int i = 0; i < 16; ++i) acc[t][i] = 0.f;
  float mrun = -1e30f, lrun = 0.f;

  const unsigned short* Kp = Kt + ((size_t)b * 1024 + lq) * 64 + hi * 8;
  const unsigned short* Vp = Vb + ((size_t)b * 128 + lq) * 1024 + hi * 8;

#pragma unroll 2
  for (int m0 = 0; m0 < 1024; m0 += 32) {
    // S^T[m][q] = sum_a K[m][a] Q[a][q]
    bf16x8 kf[4];
#pragma unroll
    for (int kc = 0; kc < 4; ++kc) kf[kc] = ld_frag(Kp + (size_t)m0 * 64 + kc * 16);
    f32x16 sa;
#pragma unroll
    for (int i = 0; i < 16; ++i) sa[i] = 0.f;
#pragma unroll
    for (int kc = 0; kc < 4; ++kc)
      sa = __builtin_amdgcn_mfma_f32_32x32x16_bf16(kf[kc], qf[kc], sa, 0, 0, 0);

    // online softmax; lane owns q=lq, m values at crow(r,hi)
    float sv[16];
#pragma unroll
    for (int r = 0; r < 16; ++r) sv[r] = sa[r];
    float cm = sv[0];
#pragma unroll
    for (int r = 1; r < 16; ++r) cm = fmaxf(cm, sv[r]);
    cm = fmaxf(cm, __shfl_xor(cm, 32));
    bool need = __any(cm > mrun);
    if (need) {
      float mnew = fmaxf(mrun, cm);
      float rsc = __expf(mrun - mnew);
      lrun *= rsc;
      mrun = mnew;
      float rr[16];
#pragma unroll
      for (int r = 0; r < 16; ++r)
        rr[r] = __shfl(rsc, (r & 3) + 8 * (r >> 2) + 4 * hi, 32);
#pragma unroll
      for (int t = 0; t < 4; ++t)
#pragma unroll
        for (int r = 0; r < 16; ++r) acc[t][r] *= rr[r];
    }
    float p[16];
    float ls = 0.f;
#pragma unroll
    for (int r = 0; r < 16; ++r) { p[r] = __expf(sv[r] - mrun); ls += p[r]; }
    ls += __shfl_xor(ls, 32);
    lrun += ls;

    // P -> bf16 A-fragments via pack + permlane32_swap
    unsigned int wpk[8];
#pragma unroll
    for (int i = 0; i < 8; ++i)
      wpk[i] = (unsigned int)f2bf(p[2 * i]) | ((unsigned int)f2bf(p[2 * i + 1]) << 16);
    auto s01 = __builtin_amdgcn_permlane32_swap(wpk[0], wpk[2], false, false);
    auto s23 = __builtin_amdgcn_permlane32_swap(wpk[1], wpk[3], false, false);
    auto s45 = __builtin_amdgcn_permlane32_swap(wpk[4], wpk[6], false, false);
    auto s67 = __builtin_amdgcn_permlane32_swap(wpk[5], wpk[7], false, false);
    uint4v f0 = {(unsigned int)s01[0], (unsigned int)s23[0], (unsigned int)s01[1],
                 (unsigned int)s23[1]};
    uint4v f1 = {(unsigned int)s45[0], (unsigned int)s67[0], (unsigned int)s45[1],
                 (unsigned int)s67[1]};
    bf16x8 pf0 = __builtin_bit_cast(bf16x8, f0);
    bf16x8 pf1 = __builtin_bit_cast(bf16x8, f1);

    // PV: O[q][vc] += P[q][m] * V^T[m][vc]  (B-frags from V[vc][m] storage)
#pragma unroll
    for (int t = 0; t < 4; ++t) {
      bf16x8 vf0 = ld_frag(Vp + (size_t)(t * 32) * 1024 + m0);
      bf16x8 vf1 = ld_frag(Vp + (size_t)(t * 32) * 1024 + m0 + 16);
      acc[t] = __builtin_amdgcn_mfma_f32_32x32x16_bf16(pf0, vf0, acc[t], 0, 0, 0);
      acc[t] = __builtin_amdgcn_mfma_f32_32x32x16_bf16(pf1, vf1, acc[t], 0, 0, 0);
    }
  }

  // normalize + store O tile to LDS (swizzled rows)
  float linv = 1.0f / lrun;
  float li[16];
#pragma unroll
  for (int r = 0; r < 16; ++r)
    li[r] = __shfl(linv, (r & 3) + 8 * (r >> 2) + 4 * hi, 32);
  unsigned short* so = sO[w];
#pragma unroll
  for (int t = 0; t < 4; ++t)
#pragma unroll
    for (int r = 0; r < 16; ++r) {
      int q = (r & 3) + 8 * (r >> 2) + 4 * hi;
      int col = t * 32 + lq;
      so[q * 128 + (col ^ ((q & 15) << 3))] = f2bf(acc[t][r] * li[r]);
    }
  __syncthreads();

  // proj: Z^T[c][q] = wproj[c][vc] * O[q][vc]
  bf16x8 of[8];
#pragma unroll
  for (int kc = 0; kc < 8; ++kc) {
    int colr = kc * 16 + hi * 8;
    of[kc] = ld_frag(&so[lq * 128 + (colr ^ ((lq & 15) << 3))]);
  }
#pragma unroll
  for (int cg = 0; cg < 2; ++cg) {
    f32x16 z[4];
#pragma unroll
    for (int t = 0; t < 4; ++t)
#pragma unroll
      for (int i = 0; i < 16; ++i) z[t][i] = 0.f;
#pragma unroll
    for (int ct = 0; ct < 4; ++ct) {
      const unsigned short* wp = wpb + (size_t)(cg * 128 + ct * 32 + lq) * 128 + hi * 8;
#pragma unroll
      for (int kc = 0; kc < 8; ++kc) {
        bf16x8 wf = ld_frag(wp + kc * 16);
        z[ct] = __builtin_amdgcn_mfma_f32_32x32x16_bf16(wf, of[kc], z[ct], 0, 0, 0);
      }
    }
#pragma unroll
    for (int ct = 0; ct < 4; ++ct)
#pragma unroll
      for (int r = 0; r < 16; ++r) {
        int c = cg * 128 + ct * 32 + (r & 3) + 8 * (r >> 2) + 4 * hi;
        float val = z[ct][r] * bnsc[c] + bnsh[c];
        yact[((size_t)(b * 256 + c)) * 16384 + q0 + lq] = f2bf(silu_f(val));
      }
  }
}

// ---------------- dw3x3 + pointwise mix + BN + SiLU + residual ----------------
__global__ __launch_bounds__(256, 2) void dwpw_kernel(
    const __hip_bfloat16* __restrict__ yact, const float* __restrict__ dww,
    const float* __restrict__ pwt, const float* __restrict__ x,
    const float* __restrict__ mg, const float* __restrict__ mb2,
    const float* __restrict__ mmu, const float* __restrict__ mvv,
    float* __restrict__ out) {
  __shared__ float sH[4 * 4 * 36];
  __shared__ float sD[4 * 64];
  __shared__ float sOut[256 * 65];
  const int tid = threadIdx.x;
  const int b = blockIdx.z;
  const int r0 = blockIdx.y * 2;
  const int c0 = blockIdx.x * 32;
  float acc[4][16] = {};
  const int o0 = (tid & 63) * 4;
  const int ph = tid >> 6;
  const int dcc = tid >> 6, dp = tid & 63, dpr = dp >> 5, dpc = dp & 31;
  for (int c = 0; c < 256; c += 4) {
    __syncthreads();
    for (int s = tid; s < 544; s += 256) {
      int cc = s / 136, rem = s % 136;
      int r = rem / 34, col = rem % 34;
      int gr = r0 - 1 + r, gc = c0 - 1 + col;
      float v = 0.f;
      if (gr >= 0 && gr < 128 && gc >= 0 && gc < 128)
        v = __bfloat162float(yact[(((size_t)b * 256 + c + cc) * 128 + gr) * 128 + gc]);
      sH[(cc * 4 + r) * 36 + col] = v;
    }
    __syncthreads();
    {
      const float* w9 = dww + (c + dcc) * 9;
      float sum = 0.f;
#pragma unroll
      for (int i = 0; i < 3; ++i)
#pragma unroll
        for (int j = 0; j < 3; ++j)
          sum += sH[(dcc * 4 + dpr + i) * 36 + dpc + j] * w9[i * 3 + j];
      sD[dcc * 64 + dp] = sum;
    }
    __syncthreads();
#pragma unroll
    for (int cc = 0; cc < 4; ++cc) {
      float4 w4 = *reinterpret_cast<const float4*>(&pwt[(c + cc) * 256 + o0]);
      const float4* d4p = reinterpret_cast<const float4*>(&sD[cc * 64 + ph * 16]);
      float wv4[4] = {w4.x, w4.y, w4.z, w4.w};
#pragma unroll
      for (int k = 0; k < 4; ++k) {
        float4 d = d4p[k];
        float dv[4] = {d.x, d.y, d.z, d.w};
#pragma unroll
        for (int oi = 0; oi < 4; ++oi)
#pragma unroll
          for (int kk = 0; kk < 4; ++kk) acc[oi][k * 4 + kk] += wv4[oi] * dv[kk];
      }
    }
  }
  __syncthreads();
#pragma unroll
  for (int oi = 0; oi < 4; ++oi)
#pragma unroll
    for (int k = 0; k < 16; ++k) sOut[(o0 + oi) * 65 + ph * 16 + k] = acc[oi][k];
  __syncthreads();
  const int lane = tid & 63;
  for (int i = 0; i < 64; ++i) {
    int o = (tid >> 6) + i * 4;
    float z = sOut[o * 65 + lane];
    float inv = mg[o] / sqrtf(mvv[o] + EPSV);
    float zb = z * inv + (mb2[o] - mmu[o] * inv);
    int pr = lane >> 5, pc = lane & 31;
    size_t gidx = (((size_t)b * 256 + o) * 128 + r0 + pr) * 128 + c0 + pc;
    out[gidx] = x[gidx] + silu_f(zb);
  }
}

extern "C" void kernel_launch(void* const* d_in, const int* in_sizes, int n_in,
                              void* d_out, int out_size, void* d_ws, size_t ws_size,
                              hipStream_t stream) {
  const float* x     = (const float*)d_in[0];
  const float* wq    = (const float*)d_in[1];
  const float* wk    = (const float*)d_in[2];
  const float* wvp   = (const float*)d_in[3];
  const float* wproj = (const float*)d_in[4];
  const float* bng   = (const float*)d_in[5];
  const float* bnb   = (const float*)d_in[6];
  const float* bnm   = (const float*)d_in[7];
  const float* bnv   = (const float*)d_in[8];
  const float* dww   = (const float*)d_in[9];
  const float* pww   = (const float*)d_in[10];
  const float* mg    = (const float*)d_in[11];
  const float* mb2   = (const float*)d_in[12];
  const float* mmu   = (const float*)d_in[13];
  const float* mvv   = (const float*)d_in[14];
  float* out = (float*)d_out;

  float* ws  = (float*)d_ws;
  float* xkv = ws;                       // 2,097,152 f
  float* pwt = xkv + 2097152;            //    65,536 f
  float* bnsc = pwt + 65536;             //       256 f
  float* bnsh = bnsc + 256;              //       256 f
  unsigned short* Qt  = (unsigned short*)(bnsh + 256);   // 8*16384*64
  unsigned short* Kt  = Qt + (size_t)8 * 16384 * 64;     // 8*1024*64
  unsigned short* Vbf = Kt + (size_t)8 * 1024 * 64;      // 8*128*1024
  unsigned short* wpb = Vbf + (size_t)8 * 128 * 1024;    // 256*128
  unsigned short* yact = wpb + 32768;                    // 8*256*16384

  pool_kernel<<<8192, 256, 0, stream>>>(x, xkv);
  transpose_pw<<<dim3(8, 8), 256, 0, stream>>>(pww, pwt);
  prep_kernel<<<130, 256, 0, stream>>>(wproj, bng, bnb, bnm, bnv, wpb, bnsc, bnsh);
  gemm_wx<1><<<dim3(256, 1, 8), 256, 0, stream>>>(wq, x, Qt, 16384, 0.125f);
  gemm_wx<1><<<dim3(16, 1, 8), 256, 0, stream>>>(wk, xkv, Kt, 1024, 1.0f);
  gemm_wx<2><<<dim3(16, 2, 8), 256, 0, stream>>>(wvp, xkv, Vbf, 1024, 1.0f);
  attn_mfma<<<dim3(128, 8), 256, 0, stream>>>(Qt, Kt, Vbf, wpb, bnsc, bnsh, yact);
  dwpw_kernel<<<dim3(4, 64, 8), 256, 0, stream>>>((const __hip_bfloat16*)yact, dww, pwt, x,
                                                  mg, mb2, mmu, mvv, out);
}

// Round 3
// 481.717 us; speedup vs baseline: 4.2336x; 2.0394x over previous
//
#include <hip/hip_runtime.h>
#include <hip/hip_bf16.h>
#include <math.h>

#define EPSV 1e-5f

typedef short bf16x8 __attribute__((ext_vector_type(8)));
typedef float f32x16 __attribute__((ext_vector_type(16)));
typedef unsigned int uint4v __attribute__((ext_vector_type(4)));

__device__ __forceinline__ float silu_f(float v) { return v / (1.0f + __expf(-v)); }

__device__ __forceinline__ unsigned short f2bf(float f) {
  __hip_bfloat16 h = __float2bfloat16(f);
  return __builtin_bit_cast(unsigned short, h);
}

__device__ __forceinline__ bf16x8 ld_frag(const unsigned short* p) {
  return *reinterpret_cast<const bf16x8*>(p);
}

// ---------------- 4x4 average pool: x[8,256,128,128] -> xkv[8,256,32,32] ----------------
__global__ __launch_bounds__(256) void pool_kernel(const float* __restrict__ x,
                                                   float* __restrict__ xkv) {
  int idx = blockIdx.x * 256 + threadIdx.x;
  int m = idx & 1023, bc = idx >> 10;
  int hh = m >> 5, ww = m & 31;
  const float* base = x + ((size_t)bc << 14) + (size_t)(hh * 4) * 128 + ww * 4;
  float s = 0.f;
#pragma unroll
  for (int i = 0; i < 4; ++i) {
    float4 v = *reinterpret_cast<const float4*>(base + i * 128);
    s += v.x + v.y + v.z + v.w;
  }
  xkv[idx] = s * 0.0625f;
}

// ---------------- prep: wproj->bf16, BN scale/shift ----------------
__global__ __launch_bounds__(256) void prep_kernel(const float* __restrict__ wproj,
                                                   const float* __restrict__ bng,
                                                   const float* __restrict__ bnb,
                                                   const float* __restrict__ bnm,
                                                   const float* __restrict__ bnv,
                                                   unsigned short* __restrict__ wpb,
                                                   float* __restrict__ bnsc,
                                                   float* __restrict__ bnsh) {
  int i = blockIdx.x * 256 + threadIdx.x;
  if (i < 32768) wpb[i] = f2bf(wproj[i]);
  else if (i < 33024) {
    int c = i - 32768;
    float inv = bng[c] / sqrtf(bnv[c] + EPSV);
    bnsc[c] = inv;
    bnsh[c] = bnb[c] - bnm[c] * inv;
  }
}

// ---------------- prep: pack pw_w into MFMA A-fragment order, bf16 ----------------
__global__ __launch_bounds__(256) void prep_pw(const float* __restrict__ pww,
                                               unsigned short* __restrict__ pwPack) {
  int f = blockIdx.x * 256 + threadIdx.x;  // 65536
  int j = f & 7, lane = (f >> 3) & 63, ks = (f >> 9) & 15, mt = f >> 13;
  int o = mt * 32 + (lane & 31);
  int cc = ks * 16 + (lane >> 5) * 8 + j;
  pwPack[f] = f2bf(pww[o * 256 + cc]);
}

// ---------------- C = alpha * W[R][256] @ X[b][256][Ncol], bf16 out ----------------
template <int MODE>
__global__ __launch_bounds__(256, 4) void gemm_wx(const float* __restrict__ W,
                                                  const float* __restrict__ X,
                                                  unsigned short* __restrict__ C, int Ncol,
                                                  float alpha) {
  __shared__ float sW[64 * 68];
  __shared__ float sX[64 * 68];
  const int tid = threadIdx.x;
  const int n0 = blockIdx.x * 64, m0 = blockIdx.y * 64;
  const int Rows = gridDim.y * 64;
  const size_t xoff = (size_t)blockIdx.z * 256 * (size_t)Ncol;
  const int tm4 = (tid >> 4) * 4, tn4 = (tid & 15) * 4;
  float acc[4][4] = {};
  for (int k0 = 0; k0 < 256; k0 += 64) {
    __syncthreads();
#pragma unroll
    for (int i = 0; i < 16; ++i) {
      int flat = tid + i * 256;
      int kk = flat & 63, mm = flat >> 6;
      sW[kk * 68 + mm] = W[(m0 + mm) * 256 + k0 + kk];
      sX[kk * 68 + mm] = X[xoff + (size_t)(k0 + kk) * Ncol + n0 + mm];
    }
    __syncthreads();
#pragma unroll 8
    for (int k = 0; k < 64; ++k) {
      float4 a4 = *reinterpret_cast<const float4*>(&sW[k * 68 + tm4]);
      float4 b4 = *reinterpret_cast<const float4*>(&sX[k * 68 + tn4]);
      float av[4] = {a4.x, a4.y, a4.z, a4.w};
      float bv[4] = {b4.x, b4.y, b4.z, b4.w};
#pragma unroll
      for (int i = 0; i < 4; ++i)
#pragma unroll
        for (int j = 0; j < 4; ++j) acc[i][j] += av[i] * bv[j];
    }
  }
  if (MODE == 1) {
    const size_t coff = (size_t)blockIdx.z * (size_t)Ncol * Rows;
#pragma unroll
    for (int j = 0; j < 4; ++j) {
      ushort4 o;
      o.x = f2bf(acc[0][j] * alpha); o.y = f2bf(acc[1][j] * alpha);
      o.z = f2bf(acc[2][j] * alpha); o.w = f2bf(acc[3][j] * alpha);
      *reinterpret_cast<ushort4*>(&C[coff + (size_t)(n0 + tn4 + j) * Rows + m0 + tm4]) = o;
    }
  } else {
    const size_t coff = (size_t)blockIdx.z * (size_t)Rows * Ncol;
#pragma unroll
    for (int i = 0; i < 4; ++i) {
      ushort4 o;
      o.x = f2bf(acc[i][0] * alpha); o.y = f2bf(acc[i][1] * alpha);
      o.z = f2bf(acc[i][2] * alpha); o.w = f2bf(acc[i][3] * alpha);
      *reinterpret_cast<ushort4*>(&C[coff + (size_t)(m0 + tm4 + i) * Ncol + n0 + tn4]) = o;
    }
  }
}

// ---------------- MFMA flash attention + proj + BN + SiLU -> yact bf16 ----------------
__global__ __launch_bounds__(256, 2) void attn_mfma(
    const unsigned short* __restrict__ Qt, const unsigned short* __restrict__ Kt,
    const unsigned short* __restrict__ Vb, const unsigned short* __restrict__ wpb,
    const float* __restrict__ bnsc, const float* __restrict__ bnsh,
    unsigned short* __restrict__ yact) {
  __shared__ unsigned short sO[4][32 * 128];
  const int tid = threadIdx.x;
  const int w = tid >> 6, l = tid & 63;
  const int lq = l & 31, hi = l >> 5;
  const int b = blockIdx.y;
  const int q0 = blockIdx.x * 128 + w * 32;

  const unsigned short* Qp = Qt + ((size_t)b * 16384 + q0 + lq) * 64 + hi * 8;
  bf16x8 qf[4];
#pragma unroll
  for (int kc = 0; kc < 4; ++kc) qf[kc] = ld_frag(Qp + kc * 16);

  f32x16 acc[4];
#pragma unroll
  for (int t = 0; t < 4; ++t)
#pragma unroll
    for (int i = 0; i < 16; ++i) acc[t][i] = 0.f;
  float mrun = -1e30f, lrun = 0.f;

  const unsigned short* Kp = Kt + ((size_t)b * 1024 + lq) * 64 + hi * 8;
  const unsigned short* Vp = Vb + ((size_t)b * 128 + lq) * 1024 + hi * 8;

#pragma unroll 2
  for (int m0 = 0; m0 < 1024; m0 += 32) {
    bf16x8 kf[4];
#pragma unroll
    for (int kc = 0; kc < 4; ++kc) kf[kc] = ld_frag(Kp + (size_t)m0 * 64 + kc * 16);
    f32x16 sa;
#pragma unroll
    for (int i = 0; i < 16; ++i) sa[i] = 0.f;
#pragma unroll
    for (int kc = 0; kc < 4; ++kc)
      sa = __builtin_amdgcn_mfma_f32_32x32x16_bf16(kf[kc], qf[kc], sa, 0, 0, 0);

    float sv[16];
#pragma unroll
    for (int r = 0; r < 16; ++r) sv[r] = sa[r];
    float cm = sv[0];
#pragma unroll
    for (int r = 1; r < 16; ++r) cm = fmaxf(cm, sv[r]);
    cm = fmaxf(cm, __shfl_xor(cm, 32));
    bool need = __any(cm > mrun);
    if (need) {
      float mnew = fmaxf(mrun, cm);
      float rsc = __expf(mrun - mnew);
      lrun *= rsc;
      mrun = mnew;
      float rr[16];
#pragma unroll
      for (int r = 0; r < 16; ++r)
        rr[r] = __shfl(rsc, (r & 3) + 8 * (r >> 2) + 4 * hi, 32);
#pragma unroll
      for (int t = 0; t < 4; ++t)
#pragma unroll
        for (int r = 0; r < 16; ++r) acc[t][r] *= rr[r];
    }
    float p[16];
    float ls = 0.f;
#pragma unroll
    for (int r = 0; r < 16; ++r) { p[r] = __expf(sv[r] - mrun); ls += p[r]; }
    ls += __shfl_xor(ls, 32);
    lrun += ls;

    unsigned int wpk[8];
#pragma unroll
    for (int i = 0; i < 8; ++i)
      wpk[i] = (unsigned int)f2bf(p[2 * i]) | ((unsigned int)f2bf(p[2 * i + 1]) << 16);
    auto s01 = __builtin_amdgcn_permlane32_swap(wpk[0], wpk[2], false, false);
    auto s23 = __builtin_amdgcn_permlane32_swap(wpk[1], wpk[3], false, false);
    auto s45 = __builtin_amdgcn_permlane32_swap(wpk[4], wpk[6], false, false);
    auto s67 = __builtin_amdgcn_permlane32_swap(wpk[5], wpk[7], false, false);
    uint4v f0 = {(unsigned int)s01[0], (unsigned int)s23[0], (unsigned int)s01[1],
                 (unsigned int)s23[1]};
    uint4v f1 = {(unsigned int)s45[0], (unsigned int)s67[0], (unsigned int)s45[1],
                 (unsigned int)s67[1]};
    bf16x8 pf0 = __builtin_bit_cast(bf16x8, f0);
    bf16x8 pf1 = __builtin_bit_cast(bf16x8, f1);

#pragma unroll
    for (int t = 0; t < 4; ++t) {
      bf16x8 vf0 = ld_frag(Vp + (size_t)(t * 32) * 1024 + m0);
      bf16x8 vf1 = ld_frag(Vp + (size_t)(t * 32) * 1024 + m0 + 16);
      acc[t] = __builtin_amdgcn_mfma_f32_32x32x16_bf16(pf0, vf0, acc[t], 0, 0, 0);
      acc[t] = __builtin_amdgcn_mfma_f32_32x32x16_bf16(pf1, vf1, acc[t], 0, 0, 0);
    }
  }

  float linv = 1.0f / lrun;
  float li[16];
#pragma unroll
  for (int r = 0; r < 16; ++r)
    li[r] = __shfl(linv, (r & 3) + 8 * (r >> 2) + 4 * hi, 32);
  unsigned short* so = sO[w];
#pragma unroll
  for (int t = 0; t < 4; ++t)
#pragma unroll
    for (int r = 0; r < 16; ++r) {
      int q = (r & 3) + 8 * (r >> 2) + 4 * hi;
      int col = t * 32 + lq;
      so[q * 128 + (col ^ ((q & 15) << 3))] = f2bf(acc[t][r] * li[r]);
    }
  __syncthreads();

  bf16x8 of[8];
#pragma unroll
  for (int kc = 0; kc < 8; ++kc) {
    int colr = kc * 16 + hi * 8;
    of[kc] = ld_frag(&so[lq * 128 + (colr ^ ((lq & 15) << 3))]);
  }
#pragma unroll
  for (int cg = 0; cg < 2; ++cg) {
    f32x16 z[4];
#pragma unroll
    for (int t = 0; t < 4; ++t)
#pragma unroll
      for (int i = 0; i < 16; ++i) z[t][i] = 0.f;
#pragma unroll
    for (int ct = 0; ct < 4; ++ct) {
      const unsigned short* wp = wpb + (size_t)(cg * 128 + ct * 32 + lq) * 128 + hi * 8;
#pragma unroll
      for (int kc = 0; kc < 8; ++kc) {
        bf16x8 wf = ld_frag(wp + kc * 16);
        z[ct] = __builtin_amdgcn_mfma_f32_32x32x16_bf16(wf, of[kc], z[ct], 0, 0, 0);
      }
    }
#pragma unroll
    for (int ct = 0; ct < 4; ++ct)
#pragma unroll
      for (int r = 0; r < 16; ++r) {
        int c = cg * 128 + ct * 32 + (r & 3) + 8 * (r >> 2) + 4 * hi;
        float val = z[ct][r] * bnsc[c] + bnsh[c];
        yact[((size_t)(b * 256 + c)) * 16384 + q0 + lq] = f2bf(silu_f(val));
      }
  }
}

// ---------------- depthwise 3x3: yact bf16 -> D bf16, one (b,c) plane per block --------
__global__ __launch_bounds__(256, 4) void dwconv_kernel(const unsigned short* __restrict__ yact,
                                                        const float* __restrict__ dww,
                                                        unsigned short* __restrict__ D) {
  __shared__ unsigned int sP[130 * 67];  // rows -1..128 at (r+1)*67; word0=cols-2,-1
  const int tid = threadIdx.x;
  const int bc = blockIdx.x;  // b*256 + c
  const int c = bc & 255;
  for (int s = tid; s < 130 * 67; s += 256) sP[s] = 0;
  __syncthreads();
  const unsigned int* ysrc = reinterpret_cast<const unsigned int*>(yact) + (size_t)bc * 8192;
#pragma unroll
  for (int i = 0; i < 8; ++i) {
    int wi4 = tid + 256 * i;
    uint4 v = *reinterpret_cast<const uint4*>(ysrc + (size_t)wi4 * 4);
    int row = wi4 >> 4;
    int cw = (wi4 & 15) * 4;
    unsigned int* dst = &sP[(row + 1) * 67 + 1 + cw];
    dst[0] = v.x; dst[1] = v.y; dst[2] = v.z; dst[3] = v.w;
  }
  __syncthreads();
  float w9[9];
#pragma unroll
  for (int k = 0; k < 9; ++k) w9[k] = dww[c * 9 + k];
#pragma unroll
  for (int it = 0; it < 4; ++it) {
    int u = tid + 256 * it;
    int rho = u >> 4;
    int wg = u & 15;
    float a0[8] = {}, a1[8] = {};
#pragma unroll
    for (int ir = 0; ir < 4; ++ir) {
      int srow = rho * 2 + ir;
      const unsigned int* rp = &sP[srow * 67 + 4 * wg];
      float f[12];
#pragma unroll
      for (int k = 0; k < 6; ++k) {
        unsigned int wv = rp[k];
        f[2 * k] = __builtin_bit_cast(float, wv << 16);
        f[2 * k + 1] = __builtin_bit_cast(float, wv & 0xffff0000u);
      }
      // f[k] = col (8wg - 2 + k); out col (8wg+cc) taps f[cc+1+dc], dc=0..2
      if (ir < 3) {
#pragma unroll
        for (int cc = 0; cc < 8; ++cc)
#pragma unroll
          for (int dc = 0; dc < 3; ++dc) a0[cc] += f[cc + 1 + dc] * w9[ir * 3 + dc];
      }
      if (ir > 0) {
#pragma unroll
        for (int cc = 0; cc < 8; ++cc)
#pragma unroll
          for (int dc = 0; dc < 3; ++dc) a1[cc] += f[cc + 1 + dc] * w9[(ir - 1) * 3 + dc];
      }
    }
    uint4v o0, o1;
#pragma unroll
    for (int k = 0; k < 4; ++k) {
      o0[k] = (unsigned int)f2bf(a0[2 * k]) | ((unsigned int)f2bf(a0[2 * k + 1]) << 16);
      o1[k] = (unsigned int)f2bf(a1[2 * k]) | ((unsigned int)f2bf(a1[2 * k + 1]) << 16);
    }
    size_t ob = (size_t)bc * 8192 + (size_t)(rho * 2) * 64 + wg * 4;  // words
    unsigned int* Dw = reinterpret_cast<unsigned int*>(D);
    *reinterpret_cast<uint4v*>(Dw + ob) = o0;
    *reinterpret_cast<uint4v*>(Dw + ob + 64) = o1;
  }
}

// ---------------- pointwise mix MFMA + BN + SiLU + residual ----------------
__global__ __launch_bounds__(256, 2) void pwmix_kernel(
    const unsigned short* __restrict__ D, const unsigned short* __restrict__ pwPack,
    const float* __restrict__ x, const float* __restrict__ mg,
    const float* __restrict__ mb2, const float* __restrict__ mmu,
    const float* __restrict__ mvv, float* __restrict__ out) {
  __shared__ unsigned int sDt[16384];  // Dt[px][c-pair]: word (px*128+cp) ^ ((px&7)<<2)
  __shared__ float smsc[256], smsh[256];
  const int tid = threadIdx.x;
  const int w = tid >> 6, l = tid & 63;
  const int lq = l & 31, hi = l >> 5;
  const int h = blockIdx.x, b = blockIdx.y;
  if (tid < 256) {
    float inv = mg[tid] * rsqrtf(mvv[tid] + EPSV);
    smsc[tid] = inv;
    smsh[tid] = mb2[tid] - mmu[tid] * inv;
  }
  const size_t dbase = ((size_t)b * 256) * 16384 + (size_t)h * 128;
#pragma unroll
  for (int i = 0; i < 8; ++i) {
    int cp = 64 * (i & 1) + 16 * w + (l >> 2);
    int pg = (l & 3) + 4 * (i >> 1);
    const unsigned short* g0 = D + dbase + (size_t)(cp * 2) * 16384 + pg * 8;
    bf16x8 d0 = ld_frag(g0);
    bf16x8 d1 = ld_frag(g0 + 16384);
#pragma unroll
    for (int j = 0; j < 8; ++j) {
      unsigned int word = ((unsigned int)(unsigned short)d0[j]) |
                          (((unsigned int)(unsigned short)d1[j]) << 16);
      int widx = ((pg * 8 + j) * 128 + cp) ^ (j << 2);
      sDt[widx] = word;
    }
  }
  __syncthreads();

  f32x16 z[2][4];
#pragma unroll
  for (int mti = 0; mti < 2; ++mti)
#pragma unroll
    for (int nt = 0; nt < 4; ++nt)
#pragma unroll
      for (int i = 0; i < 16; ++i) z[mti][nt][i] = 0.f;

#pragma unroll
  for (int ks = 0; ks < 16; ++ks) {
    bf16x8 a0 = ld_frag(pwPack + (size_t)(((w * 2 + 0) * 16 + ks) * 64 + l) * 8);
    bf16x8 a1 = ld_frag(pwPack + (size_t)(((w * 2 + 1) * 16 + ks) * 64 + l) * 8);
    bf16x8 bfr[4];
#pragma unroll
    for (int nt = 0; nt < 4; ++nt) {
      int word = ((nt * 32 + lq) * 128 + 8 * ks + 4 * hi) ^ ((lq & 7) << 2);
      bfr[nt] = *reinterpret_cast<const bf16x8*>(
          reinterpret_cast<const unsigned short*>(sDt) + (size_t)word * 2);
    }
#pragma unroll
    for (int nt = 0; nt < 4; ++nt) {
      z[0][nt] = __builtin_amdgcn_mfma_f32_32x32x16_bf16(a0, bfr[nt], z[0][nt], 0, 0, 0);
      z[1][nt] = __builtin_amdgcn_mfma_f32_32x32x16_bf16(a1, bfr[nt], z[1][nt], 0, 0, 0);
    }
  }

#pragma unroll
  for (int mti = 0; mti < 2; ++mti) {
    int ob = (w * 2 + mti) * 32 + 4 * hi;
#pragma unroll
    for (int r = 0; r < 16; ++r) {
      int o = ob + (r & 3) + 8 * (r >> 2);
      float sc = smsc[o], sh = smsh[o];
#pragma unroll
      for (int nt = 0; nt < 4; ++nt) {
        int px = nt * 32 + lq;
        size_t gi = (((size_t)(b * 256 + o)) << 14) + (size_t)h * 128 + px;
        float val = z[mti][nt][r] * sc + sh;
        out[gi] = x[gi] + silu_f(val);
      }
    }
  }
}

extern "C" void kernel_launch(void* const* d_in, const int* in_sizes, int n_in,
                              void* d_out, int out_size, void* d_ws, size_t ws_size,
                              hipStream_t stream) {
  const float* x     = (const float*)d_in[0];
  const float* wq    = (const float*)d_in[1];
  const float* wk    = (const float*)d_in[2];
  const float* wvp   = (const float*)d_in[3];
  const float* wproj = (const float*)d_in[4];
  const float* bng   = (const float*)d_in[5];
  const float* bnb   = (const float*)d_in[6];
  const float* bnm   = (const float*)d_in[7];
  const float* bnv   = (const float*)d_in[8];
  const float* dww   = (const float*)d_in[9];
  const float* pww   = (const float*)d_in[10];
  const float* mg    = (const float*)d_in[11];
  const float* mb2   = (const float*)d_in[12];
  const float* mmu   = (const float*)d_in[13];
  const float* mvv   = (const float*)d_in[14];
  float* out = (float*)d_out;

  char* base = (char*)d_ws;
  unsigned short* D = (unsigned short*)base;                   // 67,108,864 B (overlays below)
  float* xkv = (float*)base;                                   //  8,388,608 B
  unsigned short* Qt  = (unsigned short*)(base + 8388608);     // 16,777,216 B
  unsigned short* Kt  = (unsigned short*)(base + 25165824);    //  1,048,576 B
  unsigned short* Vbf = (unsigned short*)(base + 26214400);    //  2,097,152 B
  float* bnsc = (float*)(base + 67108864);
  float* bnsh = (float*)(base + 67109888);
  unsigned short* wpb    = (unsigned short*)(base + 67110912);
  unsigned short* pwPack = (unsigned short*)(base + 67176448);
  unsigned short* yact   = (unsigned short*)(base + 67307520); // 67,108,864 B

  pool_kernel<<<8192, 256, 0, stream>>>(x, xkv);
  prep_kernel<<<130, 256, 0, stream>>>(wproj, bng, bnb, bnm, bnv, wpb, bnsc, bnsh);
  prep_pw<<<256, 256, 0, stream>>>(pww, pwPack);
  gemm_wx<1><<<dim3(256, 1, 8), 256, 0, stream>>>(wq, x, Qt, 16384, 0.125f);
  gemm_wx<1><<<dim3(16, 1, 8), 256, 0, stream>>>(wk, xkv, Kt, 1024, 1.0f);
  gemm_wx<2><<<dim3(16, 2, 8), 256, 0, stream>>>(wvp, xkv, Vbf, 1024, 1.0f);
  attn_mfma<<<dim3(128, 8), 256, 0, stream>>>(Qt, Kt, Vbf, wpb, bnsc, bnsh, yact);
  dwconv_kernel<<<2048, 256, 0, stream>>>(yact, dww, D);
  pwmix_kernel<<<dim3(128, 8), 256, 0, stream>>>(D, pwPack, x, mg, mb2, mmu, mvv, out);
}

// Round 4
// 470.384 us; speedup vs baseline: 4.3356x; 1.0241x over previous
//
#include <hip/hip_runtime.h>
#include <hip/hip_bf16.h>
#include <math.h>

#define EPSV 1e-5f

typedef short bf16x8 __attribute__((ext_vector_type(8)));
typedef float f32x16 __attribute__((ext_vector_type(16)));
typedef unsigned int uint4v __attribute__((ext_vector_type(4)));

__device__ __forceinline__ float silu_f(float v) { return v / (1.0f + __expf(-v)); }

__device__ __forceinline__ unsigned short f2bf(float f) {
  __hip_bfloat16 h = __float2bfloat16(f);
  return __builtin_bit_cast(unsigned short, h);
}

__device__ __forceinline__ bf16x8 ld_frag(const unsigned short* p) {
  return *reinterpret_cast<const bf16x8*>(p);
}

// ---------------- 4x4 average pool: x[8,256,128,128] -> xkv[8,256,32,32] ----------------
__global__ __launch_bounds__(256) void pool_kernel(const float* __restrict__ x,
                                                   float* __restrict__ xkv) {
  int idx = blockIdx.x * 256 + threadIdx.x;
  int m = idx & 1023, bc = idx >> 10;
  int hh = m >> 5, ww = m & 31;
  const float* base = x + ((size_t)bc << 14) + (size_t)(hh * 4) * 128 + ww * 4;
  float s = 0.f;
#pragma unroll
  for (int i = 0; i < 4; ++i) {
    float4 v = *reinterpret_cast<const float4*>(base + i * 128);
    s += v.x + v.y + v.z + v.w;
  }
  xkv[idx] = s * 0.0625f;
}

// ---------------- prep: wproj->bf16, BN scale/shift ----------------
__global__ __launch_bounds__(256) void prep_kernel(const float* __restrict__ wproj,
                                                   const float* __restrict__ bng,
                                                   const float* __restrict__ bnb,
                                                   const float* __restrict__ bnm,
                                                   const float* __restrict__ bnv,
                                                   unsigned short* __restrict__ wpb,
                                                   float* __restrict__ bnsc,
                                                   float* __restrict__ bnsh) {
  int i = blockIdx.x * 256 + threadIdx.x;
  if (i < 32768) wpb[i] = f2bf(wproj[i]);
  else if (i < 33024) {
    int c = i - 32768;
    float inv = bng[c] / sqrtf(bnv[c] + EPSV);
    bnsc[c] = inv;
    bnsh[c] = bnb[c] - bnm[c] * inv;
  }
}

// ---------------- prep: pack pw_w into MFMA A-fragment order, bf16 ----------------
__global__ __launch_bounds__(256) void prep_pw(const float* __restrict__ pww,
                                               unsigned short* __restrict__ pwPack) {
  int f = blockIdx.x * 256 + threadIdx.x;  // 65536
  int j = f & 7, lane = (f >> 3) & 63, ks = (f >> 9) & 15, mt = f >> 13;
  int o = mt * 32 + (lane & 31);
  int cc = ks * 16 + (lane >> 5) * 8 + j;
  pwPack[f] = f2bf(pww[o * 256 + cc]);
}

// ---------------- C = alpha * W[R][256] @ X[b][256][Ncol], bf16 out ----------------
template <int MODE>
__global__ __launch_bounds__(256, 4) void gemm_wx(const float* __restrict__ W,
                                                  const float* __restrict__ X,
                                                  unsigned short* __restrict__ C, int Ncol,
                                                  float alpha) {
  __shared__ float sW[64 * 68];
  __shared__ float sX[64 * 68];
  const int tid = threadIdx.x;
  const int n0 = blockIdx.x * 64, m0 = blockIdx.y * 64;
  const int Rows = gridDim.y * 64;
  const size_t xoff = (size_t)blockIdx.z * 256 * (size_t)Ncol;
  const int tm4 = (tid >> 4) * 4, tn4 = (tid & 15) * 4;
  float acc[4][4] = {};
  for (int k0 = 0; k0 < 256; k0 += 64) {
    __syncthreads();
#pragma unroll
    for (int i = 0; i < 16; ++i) {
      int flat = tid + i * 256;
      int kk = flat & 63, mm = flat >> 6;
      sW[kk * 68 + mm] = W[(m0 + mm) * 256 + k0 + kk];
      sX[kk * 68 + mm] = X[xoff + (size_t)(k0 + kk) * Ncol + n0 + mm];
    }
    __syncthreads();
#pragma unroll 8
    for (int k = 0; k < 64; ++k) {
      float4 a4 = *reinterpret_cast<const float4*>(&sW[k * 68 + tm4]);
      float4 b4 = *reinterpret_cast<const float4*>(&sX[k * 68 + tn4]);
      float av[4] = {a4.x, a4.y, a4.z, a4.w};
      float bv[4] = {b4.x, b4.y, b4.z, b4.w};
#pragma unroll
      for (int i = 0; i < 4; ++i)
#pragma unroll
        for (int j = 0; j < 4; ++j) acc[i][j] += av[i] * bv[j];
    }
  }
  if (MODE == 1) {
    const size_t coff = (size_t)blockIdx.z * (size_t)Ncol * Rows;
#pragma unroll
    for (int j = 0; j < 4; ++j) {
      ushort4 o;
      o.x = f2bf(acc[0][j] * alpha); o.y = f2bf(acc[1][j] * alpha);
      o.z = f2bf(acc[2][j] * alpha); o.w = f2bf(acc[3][j] * alpha);
      *reinterpret_cast<ushort4*>(&C[coff + (size_t)(n0 + tn4 + j) * Rows + m0 + tm4]) = o;
    }
  } else {
    const size_t coff = (size_t)blockIdx.z * (size_t)Rows * Ncol;
#pragma unroll
    for (int i = 0; i < 4; ++i) {
      ushort4 o;
      o.x = f2bf(acc[i][0] * alpha); o.y = f2bf(acc[i][1] * alpha);
      o.z = f2bf(acc[i][2] * alpha); o.w = f2bf(acc[i][3] * alpha);
      *reinterpret_cast<ushort4*>(&C[coff + (size_t)(m0 + tm4 + i) * Ncol + n0 + tn4]) = o;
    }
  }
}

// ---------------- MFMA flash attention + proj + BN + SiLU -> yact bf16 ----------------
// 4 waves x 32 q. Swapped QK^T. Software-pipelined K/V loads (issue-early, T14),
// defer-max THR=8 (T13), permlane32_swap cross-half reduce.
__global__ __launch_bounds__(256, 2) void attn_mfma(
    const unsigned short* __restrict__ Qt, const unsigned short* __restrict__ Kt,
    const unsigned short* __restrict__ Vb, const unsigned short* __restrict__ wpb,
    const float* __restrict__ bnsc, const float* __restrict__ bnsh,
    unsigned short* __restrict__ yact) {
  __shared__ unsigned short sO[4][32 * 128];
  const int tid = threadIdx.x;
  const int w = tid >> 6, l = tid & 63;
  const int lq = l & 31, hi = l >> 5;
  const int b = blockIdx.y;
  const int q0 = blockIdx.x * 128 + w * 32;

  const unsigned short* Qp = Qt + ((size_t)b * 16384 + q0 + lq) * 64 + hi * 8;
  bf16x8 qf[4];
#pragma unroll
  for (int kc = 0; kc < 4; ++kc) qf[kc] = ld_frag(Qp + kc * 16);

  f32x16 acc[4];
#pragma unroll
  for (int t = 0; t < 4; ++t)
#pragma unroll
    for (int i = 0; i < 16; ++i) acc[t][i] = 0.f;
  float mrun = -1e30f, lrun = 0.f;

  const unsigned short* Kp = Kt + ((size_t)b * 1024 + lq) * 64 + hi * 8;
  const unsigned short* Vp = Vb + ((size_t)b * 128 + lq) * 1024 + hi * 8;

  // prefetch K tile 0
  bf16x8 kf[4];
#pragma unroll
  for (int kc = 0; kc < 4; ++kc) kf[kc] = ld_frag(Kp + kc * 16);

#pragma unroll 2
  for (int m0 = 0; m0 < 1024; m0 += 32) {
    // eager V loads for THIS iter (latency hides under QK + softmax)
    bf16x8 vf[8];
#pragma unroll
    for (int t = 0; t < 4; ++t) {
      vf[2 * t] = ld_frag(Vp + (size_t)(t * 32) * 1024 + m0);
      vf[2 * t + 1] = ld_frag(Vp + (size_t)(t * 32) * 1024 + m0 + 16);
    }
    __builtin_amdgcn_sched_barrier(0);  // pin the V-issue above the MFMAs

    f32x16 sa;
#pragma unroll
    for (int i = 0; i < 16; ++i) sa[i] = 0.f;
#pragma unroll
    for (int kc = 0; kc < 4; ++kc)
      sa = __builtin_amdgcn_mfma_f32_32x32x16_bf16(kf[kc], qf[kc], sa, 0, 0, 0);

    // prefetch NEXT K tile (hides under softmax+PV)
    bf16x8 kfn[4];
#pragma unroll
    for (int kc = 0; kc < 4; ++kc) kfn[kc] = ld_frag(Kp + (size_t)(m0 + 32) * 64 + kc * 16);
    __builtin_amdgcn_sched_barrier(0);  // pin the K-issue here

    float sv[16];
#pragma unroll
    for (int r = 0; r < 16; ++r) sv[r] = sa[r];
    // tree max (depth 4)
    float mx[8];
#pragma unroll
    for (int i = 0; i < 8; ++i) mx[i] = fmaxf(sv[2 * i], sv[2 * i + 1]);
#pragma unroll
    for (int i = 0; i < 4; ++i) mx[i] = fmaxf(mx[2 * i], mx[2 * i + 1]);
    float cm = fmaxf(fmaxf(mx[0], mx[1]), fmaxf(mx[2], mx[3]));
    {  // cross-half max via permlane32_swap (VALU, no LDS)
      unsigned cb = __builtin_bit_cast(unsigned, cm);
      auto sw = __builtin_amdgcn_permlane32_swap(cb, cb, false, false);
      cm = fmaxf(__builtin_bit_cast(float, (unsigned)sw[0]),
                 __builtin_bit_cast(float, (unsigned)sw[1]));
    }
    if (__any(cm > mrun + 8.0f)) {  // defer-max: rescale only on big growth
      float mnew = fmaxf(mrun, cm);
      float rsc = __expf(mrun - mnew);
      lrun *= rsc;
      mrun = mnew;
      float rr[16];
#pragma unroll
      for (int r = 0; r < 16; ++r)
        rr[r] = __shfl(rsc, (r & 3) + 8 * (r >> 2) + 4 * hi, 32);
#pragma unroll
      for (int t = 0; t < 4; ++t)
#pragma unroll
        for (int r = 0; r < 16; ++r) acc[t][r] *= rr[r];
    }
    float p[16];
#pragma unroll
    for (int r = 0; r < 16; ++r) p[r] = __expf(sv[r] - mrun);
    // tree sum
    float sm[8];
#pragma unroll
    for (int i = 0; i < 8; ++i) sm[i] = p[2 * i] + p[2 * i + 1];
#pragma unroll
    for (int i = 0; i < 4; ++i) sm[i] = sm[2 * i] + sm[2 * i + 1];
    float ls = (sm[0] + sm[1]) + (sm[2] + sm[3]);
    {
      unsigned lb = __builtin_bit_cast(unsigned, ls);
      auto sw = __builtin_amdgcn_permlane32_swap(lb, lb, false, false);
      ls = __builtin_bit_cast(float, (unsigned)sw[0]) +
           __builtin_bit_cast(float, (unsigned)sw[1]);
    }
    lrun += ls;

    unsigned int wpk[8];
#pragma unroll
    for (int i = 0; i < 8; ++i)
      wpk[i] = (unsigned int)f2bf(p[2 * i]) | ((unsigned int)f2bf(p[2 * i + 1]) << 16);
    auto s01 = __builtin_amdgcn_permlane32_swap(wpk[0], wpk[2], false, false);
    auto s23 = __builtin_amdgcn_permlane32_swap(wpk[1], wpk[3], false, false);
    auto s45 = __builtin_amdgcn_permlane32_swap(wpk[4], wpk[6], false, false);
    auto s67 = __builtin_amdgcn_permlane32_swap(wpk[5], wpk[7], false, false);
    uint4v f0 = {(unsigned int)s01[0], (unsigned int)s23[0], (unsigned int)s01[1],
                 (unsigned int)s23[1]};
    uint4v f1 = {(unsigned int)s45[0], (unsigned int)s67[0], (unsigned int)s45[1],
                 (unsigned int)s67[1]};
    bf16x8 pf0 = __builtin_bit_cast(bf16x8, f0);
    bf16x8 pf1 = __builtin_bit_cast(bf16x8, f1);

#pragma unroll
    for (int t = 0; t < 4; ++t) {
      acc[t] = __builtin_amdgcn_mfma_f32_32x32x16_bf16(pf0, vf[2 * t], acc[t], 0, 0, 0);
      acc[t] = __builtin_amdgcn_mfma_f32_32x32x16_bf16(pf1, vf[2 * t + 1], acc[t], 0, 0, 0);
    }
#pragma unroll
    for (int kc = 0; kc < 4; ++kc) kf[kc] = kfn[kc];
  }

  float linv = 1.0f / lrun;
  float li[16];
#pragma unroll
  for (int r = 0; r < 16; ++r)
    li[r] = __shfl(linv, (r & 3) + 8 * (r >> 2) + 4 * hi, 32);
  unsigned short* so = sO[w];
#pragma unroll
  for (int t = 0; t < 4; ++t)
#pragma unroll
    for (int r = 0; r < 16; ++r) {
      int q = (r & 3) + 8 * (r >> 2) + 4 * hi;
      int col = t * 32 + lq;
      so[q * 128 + (col ^ ((q & 15) << 3))] = f2bf(acc[t][r] * li[r]);
    }
  __syncthreads();

  bf16x8 of[8];
#pragma unroll
  for (int kc = 0; kc < 8; ++kc) {
    int colr = kc * 16 + hi * 8;
    of[kc] = ld_frag(&so[lq * 128 + (colr ^ ((lq & 15) << 3))]);
  }
#pragma unroll
  for (int cg = 0; cg < 2; ++cg) {
    f32x16 z[4];
#pragma unroll
    for (int t = 0; t < 4; ++t)
#pragma unroll
      for (int i = 0; i < 16; ++i) z[t][i] = 0.f;
#pragma unroll
    for (int ct = 0; ct < 4; ++ct) {
      const unsigned short* wp = wpb + (size_t)(cg * 128 + ct * 32 + lq) * 128 + hi * 8;
#pragma unroll
      for (int kc = 0; kc < 8; ++kc) {
        bf16x8 wf = ld_frag(wp + kc * 16);
        z[ct] = __builtin_amdgcn_mfma_f32_32x32x16_bf16(wf, of[kc], z[ct], 0, 0, 0);
      }
    }
#pragma unroll
    for (int ct = 0; ct < 4; ++ct)
#pragma unroll
      for (int r = 0; r < 16; ++r) {
        int c = cg * 128 + ct * 32 + (r & 3) + 8 * (r >> 2) + 4 * hi;
        float val = z[ct][r] * bnsc[c] + bnsh[c];
        yact[((size_t)(b * 256 + c)) * 16384 + q0 + lq] = f2bf(silu_f(val));
      }
  }
}

// ---------------- depthwise 3x3: yact bf16 -> D bf16, one (b,c) plane per block --------
__global__ __launch_bounds__(256, 4) void dwconv_kernel(const unsigned short* __restrict__ yact,
                                                        const float* __restrict__ dww,
                                                        unsigned short* __restrict__ D) {
  __shared__ unsigned int sP[130 * 67];
  const int tid = threadIdx.x;
  const int bc = blockIdx.x;
  const int c = bc & 255;
  for (int s = tid; s < 130 * 67; s += 256) sP[s] = 0;
  __syncthreads();
  const unsigned int* ysrc = reinterpret_cast<const unsigned int*>(yact) + (size_t)bc * 8192;
#pragma unroll
  for (int i = 0; i < 8; ++i) {
    int wi4 = tid + 256 * i;
    uint4 v = *reinterpret_cast<const uint4*>(ysrc + (size_t)wi4 * 4);
    int row = wi4 >> 4;
    int cw = (wi4 & 15) * 4;
    unsigned int* dst = &sP[(row + 1) * 67 + 1 + cw];
    dst[0] = v.x; dst[1] = v.y; dst[2] = v.z; dst[3] = v.w;
  }
  __syncthreads();
  float w9[9];
#pragma unroll
  for (int k = 0; k < 9; ++k) w9[k] = dww[c * 9 + k];
#pragma unroll
  for (int it = 0; it < 4; ++it) {
    int u = tid + 256 * it;
    int rho = u >> 4;
    int wg = u & 15;
    float a0[8] = {}, a1[8] = {};
#pragma unroll
    for (int ir = 0; ir < 4; ++ir) {
      int srow = rho * 2 + ir;
      const unsigned int* rp = &sP[srow * 67 + 4 * wg];
      float f[12];
#pragma unroll
      for (int k = 0; k < 6; ++k) {
        unsigned int wv = rp[k];
        f[2 * k] = __builtin_bit_cast(float, wv << 16);
        f[2 * k + 1] = __builtin_bit_cast(float, wv & 0xffff0000u);
      }
      if (ir < 3) {
#pragma unroll
        for (int cc = 0; cc < 8; ++cc)
#pragma unroll
          for (int dc = 0; dc < 3; ++dc) a0[cc] += f[cc + 1 + dc] * w9[ir * 3 + dc];
      }
      if (ir > 0) {
#pragma unroll
        for (int cc = 0; cc < 8; ++cc)
#pragma unroll
          for (int dc = 0; dc < 3; ++dc) a1[cc] += f[cc + 1 + dc] * w9[(ir - 1) * 3 + dc];
      }
    }
    uint4v o0, o1;
#pragma unroll
    for (int k = 0; k < 4; ++k) {
      o0[k] = (unsigned int)f2bf(a0[2 * k]) | ((unsigned int)f2bf(a0[2 * k + 1]) << 16);
      o1[k] = (unsigned int)f2bf(a1[2 * k]) | ((unsigned int)f2bf(a1[2 * k + 1]) << 16);
    }
    size_t ob = (size_t)bc * 8192 + (size_t)(rho * 2) * 64 + wg * 4;
    unsigned int* Dw = reinterpret_cast<unsigned int*>(D);
    *reinterpret_cast<uint4v*>(Dw + ob) = o0;
    *reinterpret_cast<uint4v*>(Dw + ob + 64) = o1;
  }
}

// ---------------- pointwise mix MFMA + BN + SiLU + residual ----------------
__global__ __launch_bounds__(256, 2) void pwmix_kernel(
    const unsigned short* __restrict__ D, const unsigned short* __restrict__ pwPack,
    const float* __restrict__ x, const float* __restrict__ mg,
    const float* __restrict__ mb2, const float* __restrict__ mmu,
    const float* __restrict__ mvv, float* __restrict__ out) {
  __shared__ unsigned int sDt[16384];
  __shared__ float smsc[256], smsh[256];
  const int tid = threadIdx.x;
  const int w = tid >> 6, l = tid & 63;
  const int lq = l & 31, hi = l >> 5;
  const int h = blockIdx.x, b = blockIdx.y;
  if (tid < 256) {
    float inv = mg[tid] * rsqrtf(mvv[tid] + EPSV);
    smsc[tid] = inv;
    smsh[tid] = mb2[tid] - mmu[tid] * inv;
  }
  const size_t dbase = ((size_t)b * 256) * 16384 + (size_t)h * 128;
#pragma unroll
  for (int i = 0; i < 8; ++i) {
    int cp = 64 * (i & 1) + 16 * w + (l >> 2);
    int pg = (l & 3) + 4 * (i >> 1);
    const unsigned short* g0 = D + dbase + (size_t)(cp * 2) * 16384 + pg * 8;
    bf16x8 d0 = ld_frag(g0);
    bf16x8 d1 = ld_frag(g0 + 16384);
#pragma unroll
    for (int j = 0; j < 8; ++j) {
      unsigned int word = ((unsigned int)(unsigned short)d0[j]) |
                          (((unsigned int)(unsigned short)d1[j]) << 16);
      int widx = ((pg * 8 + j) * 128 + cp) ^ (j << 2);
      sDt[widx] = word;
    }
  }
  __syncthreads();

  f32x16 z[2][4];
#pragma unroll
  for (int mti = 0; mti < 2; ++mti)
#pragma unroll
    for (int nt = 0; nt < 4; ++nt)
#pragma unroll
      for (int i = 0; i < 16; ++i) z[mti][nt][i] = 0.f;

#pragma unroll
  for (int ks = 0; ks < 16; ++ks) {
    bf16x8 a0 = ld_frag(pwPack + (size_t)(((w * 2 + 0) * 16 + ks) * 64 + l) * 8);
    bf16x8 a1 = ld_frag(pwPack + (size_t)(((w * 2 + 1) * 16 + ks) * 64 + l) * 8);
    bf16x8 bfr[4];
#pragma unroll
    for (int nt = 0; nt < 4; ++nt) {
      int word = ((nt * 32 + lq) * 128 + 8 * ks + 4 * hi) ^ ((lq & 7) << 2);
      bfr[nt] = *reinterpret_cast<const bf16x8*>(
          reinterpret_cast<const unsigned short*>(sDt) + (size_t)word * 2);
    }
#pragma unroll
    for (int nt = 0; nt < 4; ++nt) {
      z[0][nt] = __builtin_amdgcn_mfma_f32_32x32x16_bf16(a0, bfr[nt], z[0][nt], 0, 0, 0);
      z[1][nt] = __builtin_amdgcn_mfma_f32_32x32x16_bf16(a1, bfr[nt], z[1][nt], 0, 0, 0);
    }
  }

#pragma unroll
  for (int mti = 0; mti < 2; ++mti) {
    int ob = (w * 2 + mti) * 32 + 4 * hi;
#pragma unroll
    for (int r = 0; r < 16; ++r) {
      int o = ob + (r & 3) + 8 * (r >> 2);
      float sc = smsc[o], sh = smsh[o];
#pragma unroll
      for (int nt = 0; nt < 4; ++nt) {
        int px = nt * 32 + lq;
        size_t gi = (((size_t)(b * 256 + o)) << 14) + (size_t)h * 128 + px;
        float val = z[mti][nt][r] * sc + sh;
        out[gi] = x[gi] + silu_f(val);
      }
    }
  }
}

extern "C" void kernel_launch(void* const* d_in, const int* in_sizes, int n_in,
                              void* d_out, int out_size, void* d_ws, size_t ws_size,
                              hipStream_t stream) {
  const float* x     = (const float*)d_in[0];
  const float* wq    = (const float*)d_in[1];
  const float* wk    = (const float*)d_in[2];
  const float* wvp   = (const float*)d_in[3];
  const float* wproj = (const float*)d_in[4];
  const float* bng   = (const float*)d_in[5];
  const float* bnb   = (const float*)d_in[6];
  const float* bnm   = (const float*)d_in[7];
  const float* bnv   = (const float*)d_in[8];
  const float* dww   = (const float*)d_in[9];
  const float* pww   = (const float*)d_in[10];
  const float* mg    = (const float*)d_in[11];
  const float* mb2   = (const float*)d_in[12];
  const float* mmu   = (const float*)d_in[13];
  const float* mvv   = (const float*)d_in[14];
  float* out = (float*)d_out;

  char* base = (char*)d_ws;
  unsigned short* D = (unsigned short*)base;                   // overlays attn scratch
  float* xkv = (float*)base;
  unsigned short* Qt  = (unsigned short*)(base + 8388608);
  unsigned short* Kt  = (unsigned short*)(base + 25165824);
  unsigned short* Vbf = (unsigned short*)(base + 26214400);
  float* bnsc = (float*)(base + 67108864);
  float* bnsh = (float*)(base + 67109888);
  unsigned short* wpb    = (unsigned short*)(base + 67110912);
  unsigned short* pwPack = (unsigned short*)(base + 67176448);
  unsigned short* yact   = (unsigned short*)(base + 67307520);

  pool_kernel<<<8192, 256, 0, stream>>>(x, xkv);
  prep_kernel<<<130, 256, 0, stream>>>(wproj, bng, bnb, bnm, bnv, wpb, bnsc, bnsh);
  prep_pw<<<256, 256, 0, stream>>>(pww, pwPack);
  gemm_wx<1><<<dim3(256, 1, 8), 256, 0, stream>>>(wq, x, Qt, 16384, 0.125f);
  gemm_wx<1><<<dim3(16, 1, 8), 256, 0, stream>>>(wk, xkv, Kt, 1024, 1.0f);
  gemm_wx<2><<<dim3(16, 2, 8), 256, 0, stream>>>(wvp, xkv, Vbf, 1024, 1.0f);
  attn_mfma<<<dim3(128, 8), 256, 0, stream>>>(Qt, Kt, Vbf, wpb, bnsc, bnsh, yact);
  dwconv_kernel<<<2048, 256, 0, stream>>>(yact, dww, D);
  pwmix_kernel<<<dim3(128, 8), 256, 0, stream>>>(D, pwPack, x, mg, mb2, mmu, mvv, out);
}